// Round 1
// baseline (287.792 us; speedup 1.0000x reference)
//
#include <hip/hip_runtime.h>

#define NROWS 65536
#define DIM   64
#define NCODE 1024
#define KTILE 128
#define NSTAGE (NCODE / KTILE)   // 8
#define NTHR  256
#define NBLK  (NROWS / NTHR)     // 256

// One thread owns one row of x (64 floats in VGPRs). Embeddings staged in
// LDS 128 codes at a time; inner-loop LDS reads are wave-uniform ->
// same-address broadcast, conflict-free. d = x2 - 2*dot + e2 in fp32 to
// mimic the reference formula's rounding; strict-less ascending-k compare
// matches argmin first-index tie-break. Row loss = best distance (== sum
// (q-x)^2 up to fp rounding, far inside the 2.3e-2 threshold).
__global__ __launch_bounds__(NTHR) void vq_main(
    const float* __restrict__ x,
    const float* __restrict__ e,
    float* __restrict__ out,
    float* __restrict__ wsp)
{
  __shared__ float eL[KTILE * DIM];   // 32 KB
  __shared__ float e2L[KTILE];
  __shared__ float red[NTHR];

  const int t = threadIdx.x;
  const size_t row = (size_t)blockIdx.x * NTHR + t;

  // ---- load x row into registers (16x float4) ----
  float xr[DIM];
  {
    const float4* xg = reinterpret_cast<const float4*>(x + row * DIM);
    #pragma unroll
    for (int i = 0; i < DIM / 4; ++i) {
      float4 v = xg[i];
      xr[4*i+0] = v.x; xr[4*i+1] = v.y; xr[4*i+2] = v.z; xr[4*i+3] = v.w;
    }
  }
  float x2 = 0.f;
  #pragma unroll
  for (int j = 0; j < DIM; ++j) x2 = fmaf(xr[j], xr[j], x2);

  float best  = 3.4e38f;
  int   bestk = 0;

  for (int s = 0; s < NSTAGE; ++s) {
    __syncthreads();   // protect previous tile from overwrite
    {
      // stage 128 codes: thread t loads half-code (32 floats), computes
      // partial ||e||^2 from registers (avoids strided LDS re-read).
      const int c = t >> 1, h = t & 1;
      const float4* src = reinterpret_cast<const float4*>(
          e + ((size_t)(s * KTILE + c)) * DIM + h * 32);
      float4* dst = reinterpret_cast<float4*>(&eL[c * DIM + h * 32]);
      float p2 = 0.f;
      #pragma unroll
      for (int i = 0; i < 8; ++i) {
        float4 v = src[i];
        dst[i] = v;
        p2 = fmaf(v.x, v.x, fmaf(v.y, v.y, fmaf(v.z, v.z, fmaf(v.w, v.w, p2))));
      }
      float o = __shfl_xor(p2, 1);
      if (h == 0) e2L[c] = p2 + o;
    }
    __syncthreads();

    #pragma unroll 1
    for (int k = 0; k < KTILE; k += 4) {
      float a[4][4];
      #pragma unroll
      for (int c = 0; c < 4; ++c) {
        a[c][0] = 0.f; a[c][1] = 0.f; a[c][2] = 0.f; a[c][3] = 0.f;
      }
      const float4* ep0 = reinterpret_cast<const float4*>(&eL[(k + 0) * DIM]);
      const float4* ep1 = reinterpret_cast<const float4*>(&eL[(k + 1) * DIM]);
      const float4* ep2 = reinterpret_cast<const float4*>(&eL[(k + 2) * DIM]);
      const float4* ep3 = reinterpret_cast<const float4*>(&eL[(k + 3) * DIM]);
      #pragma unroll
      for (int i = 0; i < DIM / 4; ++i) {
        float4 v0 = ep0[i], v1 = ep1[i], v2 = ep2[i], v3 = ep3[i];
        a[0][0] = fmaf(xr[4*i+0], v0.x, a[0][0]);
        a[0][1] = fmaf(xr[4*i+1], v0.y, a[0][1]);
        a[0][2] = fmaf(xr[4*i+2], v0.z, a[0][2]);
        a[0][3] = fmaf(xr[4*i+3], v0.w, a[0][3]);
        a[1][0] = fmaf(xr[4*i+0], v1.x, a[1][0]);
        a[1][1] = fmaf(xr[4*i+1], v1.y, a[1][1]);
        a[1][2] = fmaf(xr[4*i+2], v1.z, a[1][2]);
        a[1][3] = fmaf(xr[4*i+3], v1.w, a[1][3]);
        a[2][0] = fmaf(xr[4*i+0], v2.x, a[2][0]);
        a[2][1] = fmaf(xr[4*i+1], v2.y, a[2][1]);
        a[2][2] = fmaf(xr[4*i+2], v2.z, a[2][2]);
        a[2][3] = fmaf(xr[4*i+3], v2.w, a[2][3]);
        a[3][0] = fmaf(xr[4*i+0], v3.x, a[3][0]);
        a[3][1] = fmaf(xr[4*i+1], v3.y, a[3][1]);
        a[3][2] = fmaf(xr[4*i+2], v3.z, a[3][2]);
        a[3][3] = fmaf(xr[4*i+3], v3.w, a[3][3]);
      }
      #pragma unroll
      for (int c = 0; c < 4; ++c) {
        float dot = (a[c][0] + a[c][1]) + (a[c][2] + a[c][3]);
        float d = (x2 - 2.0f * dot) + e2L[k + c];
        int kk = s * KTILE + k + c;
        if (d < best) { best = d; bestk = kk; }
      }
    }
  }

  // ---- write quantized row (gather from global e; 256 KB lives in L2) ----
  {
    const float4* qg = reinterpret_cast<const float4*>(e + (size_t)bestk * DIM);
    float4* og = reinterpret_cast<float4*>(out + row * DIM);
    #pragma unroll
    for (int i = 0; i < DIM / 4; ++i) og[i] = qg[i];
  }

  // ---- deterministic block reduction of per-row loss ----
  red[t] = best;
  __syncthreads();
  #pragma unroll
  for (int w = NTHR / 2; w > 0; w >>= 1) {
    if (t < w) red[t] += red[t + w];
    __syncthreads();
  }
  if (t == 0) wsp[blockIdx.x] = red[0];
}

__global__ __launch_bounds__(NBLK) void vq_fin(const float* __restrict__ wsp,
                                               float* __restrict__ loss)
{
  __shared__ float red[NBLK];
  const int t = threadIdx.x;
  red[t] = wsp[t];
  __syncthreads();
  #pragma unroll
  for (int w = NBLK / 2; w > 0; w >>= 1) {
    if (t < w) red[t] += red[t + w];
    __syncthreads();
  }
  if (t == 0)
    loss[0] = red[0] * (1.25f / (float)((size_t)NROWS * DIM));
}

extern "C" void kernel_launch(void* const* d_in, const int* in_sizes, int n_in,
                              void* d_out, int out_size, void* d_ws, size_t ws_size,
                              hipStream_t stream) {
  const float* x = (const float*)d_in[0];   // [65536, 64] flattened
  const float* e = (const float*)d_in[1];   // [1024, 64]
  float* out = (float*)d_out;               // [65536*64] quantized_st + [1] loss
  float* wsp = (float*)d_ws;                // 256 block partials

  vq_main<<<NBLK, NTHR, 0, stream>>>(x, e, out, wsp);
  vq_fin<<<1, NBLK, 0, stream>>>(wsp, out + (size_t)NROWS * DIM);
}